// Round 1
// baseline (1417.792 us; speedup 1.0000x reference)
//
#include <hip/hip_runtime.h>
#include <stdint.h>

#define B_TOT   16384
#define NNBR    20
#define NODE_D  172
#define TIME_D  100
#define KEY_D   444
#define OUT_D   272      // = NODE_D + TIME_D
#define KPAD    448      // KEY_D padded to x32
#define NPAD    640      // 2*OUT_D=544 padded to 5*128
#define CHUNKS  4
#define CB      (B_TOT/CHUNKS)   // 4096 batch rows per chunk
#define CROWS   (CB*NNBR)        // 81920 kv rows per chunk
#define K2PAD   288              // 272 padded to x32 (Q / residual GEMMs)

typedef __attribute__((ext_vector_type(4))) float          f32x4;
typedef __attribute__((ext_vector_type(8))) short          bfx8;
typedef __attribute__((ext_vector_type(4))) unsigned short usx4;
typedef __attribute__((ext_vector_type(8))) unsigned short usx8;

__device__ __forceinline__ unsigned short f2bf(float f) {
  union { float f; unsigned u; } v; v.f = f;
  return (unsigned short)((v.u + 0x7FFFu + ((v.u >> 16) & 1u)) >> 16);  // RTNE
}
__device__ __forceinline__ float bf2f(unsigned short h) {
  union { unsigned u; float f; } v; v.u = ((unsigned)h) << 16; return v.f;
}
__device__ __forceinline__ void async16(const void* g, void* l) {
  __builtin_amdgcn_global_load_lds((const __attribute__((address_space(1))) void*)g,
                                   (__attribute__((address_space(3))) void*)l, 16, 0, 0);
}

// ---------------------------------------------------------------- pack weights
// Bkv: [NPAD][KPAD] n-major bf16, cols 0..271 = Wk rows, 272..543 = Wv rows, rest 0
// Bq/Br: [K2PAD][K2PAD] n-major bf16, zero-padded
__global__ __launch_bounds__(256) void pack_w(
    const float* __restrict__ Wk, const float* __restrict__ Wv,
    const float* __restrict__ Wq, const float* __restrict__ Wr,
    unsigned short* __restrict__ Bkv, unsigned short* __restrict__ Bq,
    unsigned short* __restrict__ Br) {
  int idx = blockIdx.x * 256 + threadIdx.x;
  if (idx < NPAD * KPAD) {
    int j = idx / KPAD, k = idx % KPAD;
    float v = 0.f;
    if (k < KEY_D) {
      if (j < OUT_D)        v = Wk[j * KEY_D + k];
      else if (j < 2*OUT_D) v = Wv[(j - OUT_D) * KEY_D + k];
    }
    Bkv[idx] = f2bf(v);
  }
  if (idx < K2PAD * K2PAD) {
    int j = idx / K2PAD, k = idx % K2PAD;
    bool in = (j < OUT_D) && (k < OUT_D);
    Bq[idx] = f2bf(in ? Wq[j * OUT_D + k] : 0.f);
    Br[idx] = f2bf(in ? Wr[j * OUT_D + k] : 0.f);
  }
}

// ---------------------------------------------------------------- K/V GEMM
// A[row][k] = concat(nbr_node,nbr_edge,nbr_time)[row], row = global (b,n) index.
// KV[row][0..543] bf16 (chunk-local rows), cols 0..271 = K, 272..543 = V.
__global__ __launch_bounds__(256) void kv_gemm(
    const float* __restrict__ nbrF, const float* __restrict__ edgeF,
    const float* __restrict__ timeF, const unsigned short* __restrict__ Bkv,
    unsigned short* __restrict__ KV, int row0) {
  __shared__ unsigned short sm[18432];  // A[128][40] @0 | B[128][32] @5120 ; epilogue reuses all
  const int t = threadIdx.x;
  const int w = t >> 6, l = t & 63, l15 = l & 15, quad = l >> 4;
  const int wm = w >> 1, wn = w & 1;
  const int n0 = blockIdx.x * 128;
  const int m0 = blockIdx.y * 128;
  f32x4 acc[4][4];
#pragma unroll
  for (int i = 0; i < 4; ++i)
#pragma unroll
    for (int j = 0; j < 4; ++j) acc[i][j] = (f32x4){0.f, 0.f, 0.f, 0.f};

  const int arp = t >> 3;          // row-in-pass (0..31)
  const int akq = (t & 7) * 4;     // k offset within 32-window (0..28)

  for (int k0 = 0; k0 < KPAD; k0 += 32) {
    const int k = k0 + akq;
    // stage A: 128 rows x 32 k, fp32 gather -> bf16, LDS row stride 40 (bank-safe)
#pragma unroll
    for (int p = 0; p < 4; ++p) {
      const int r = p * 32 + arp;
      const long g = (long)row0 + m0 + r;
      f32x4 v = (f32x4){0.f, 0.f, 0.f, 0.f};
      if (k < NODE_D)        v = *(const f32x4*)(nbrF  + g * NODE_D + k);
      else if (k < 2*NODE_D) v = *(const f32x4*)(edgeF + g * NODE_D + (k - NODE_D));
      else if (k < KEY_D)    v = *(const f32x4*)(timeF + g * TIME_D + (k - 2*NODE_D));
      usx4 h; h[0] = f2bf(v[0]); h[1] = f2bf(v[1]); h[2] = f2bf(v[2]); h[3] = f2bf(v[3]);
      *(usx4*)&sm[r * 40 + akq] = h;
    }
    // stage B: [128 cols][32 k] contiguous, direct-to-LDS 16B
#pragma unroll
    for (int rr = 0; rr < 2; ++rr) {
      const int lin = (rr * 256 + t) * 16;
      const int col = lin >> 6;
      const int kb  = lin & 63;
      const char* gp = (const char*)Bkv + ((size_t)(n0 + col) * KPAD + k0) * 2 + kb;
      async16(gp, &sm[5120 + w * 512 + rr * 2048]);
    }
    __syncthreads();
    bfx8 af[4], bf[4];
#pragma unroll
    for (int mf = 0; mf < 4; ++mf)
      af[mf] = *(const bfx8*)&sm[(wm * 64 + mf * 16 + l15) * 40 + quad * 8];
#pragma unroll
    for (int nf = 0; nf < 4; ++nf)
      bf[nf] = *(const bfx8*)&sm[5120 + (wn * 64 + nf * 16 + l15) * 32 + quad * 8];
#pragma unroll
    for (int mf = 0; mf < 4; ++mf)
#pragma unroll
      for (int nf = 0; nf < 4; ++nf)
        acc[mf][nf] = __builtin_amdgcn_mfma_f32_16x16x32_bf16(af[mf], bf[nf], acc[mf][nf], 0, 0, 0);
    __syncthreads();
  }
  // epilogue: per-wave 64x64 tile -> LDS (stride 72 bf16) -> 16B coalesced stores
  unsigned short* tile = &sm[w * 4608];
#pragma unroll
  for (int mf = 0; mf < 4; ++mf)
#pragma unroll
    for (int nf = 0; nf < 4; ++nf)
#pragma unroll
      for (int r = 0; r < 4; ++r)
        tile[(mf * 16 + quad * 4 + r) * 72 + nf * 16 + l15] = f2bf(acc[mf][nf][r]);
  __syncthreads();
#pragma unroll
  for (int i = 0; i < 8; ++i) {
    const int lin = (i * 64 + l) * 16;
    const int row = lin >> 7;
    const int cb  = lin & 127;
    const int gcol = n0 + wn * 64 + (cb >> 1);
    if (gcol < 2 * OUT_D) {
      usx8 v = *(const usx8*)((const char*)tile + row * 144 + cb);
      const size_t grow = (size_t)m0 + wm * 64 + row;  // chunk-local kv row
      *(usx8*)((char*)KV + grow * (2 * OUT_D * 2) + (size_t)gcol * 2) = v;
    }
  }
}

// ---------------------------------------------------------------- Q GEMM
// Q[b][0..287] bf16 (cols 272..287 are genuine zeros via zero-padded Bq)
__global__ __launch_bounds__(256) void q_gemm(
    const float* __restrict__ nodeF, const float* __restrict__ timeF,
    const unsigned short* __restrict__ Bq, unsigned short* __restrict__ Q) {
  __shared__ unsigned short sm[11776];  // A[64][40] @0 | B[288][32] @2560
  const int t = threadIdx.x;
  const int w = t >> 6, l = t & 63, l15 = l & 15, quad = l >> 4;
  const int wm = w >> 1, wn = w & 1;
  const int m0 = blockIdx.x * 64;
  f32x4 acc[2][9];
#pragma unroll
  for (int i = 0; i < 2; ++i)
#pragma unroll
    for (int j = 0; j < 9; ++j) acc[i][j] = (f32x4){0.f, 0.f, 0.f, 0.f};

  for (int k0 = 0; k0 < K2PAD; k0 += 32) {
#pragma unroll
    for (int p = 0; p < 2; ++p) {
      const int idx = p * 256 + t;
      const int r = idx >> 3;
      const int kq = (idx & 7) * 4;
      const int k = k0 + kq;
      const long g = m0 + r;
      f32x4 v = (f32x4){0.f, 0.f, 0.f, 0.f};
      if (k < NODE_D)     v = *(const f32x4*)(nodeF + g * NODE_D + k);
      else if (k < OUT_D) v = *(const f32x4*)(timeF + g * TIME_D + (k - NODE_D));
      usx4 h; h[0] = f2bf(v[0]); h[1] = f2bf(v[1]); h[2] = f2bf(v[2]); h[3] = f2bf(v[3]);
      *(usx4*)&sm[r * 40 + kq] = h;
    }
#pragma unroll
    for (int rr = 0; rr < 5; ++rr) {
      const int i16 = rr * 256 + t;
      if (i16 < 1152) {  // wave-uniform predicate (waves are 64-aligned)
        const int col = i16 >> 2;
        const int kb  = (i16 & 3) * 16;
        const char* gp = (const char*)Bq + ((size_t)col * K2PAD + k0) * 2 + kb;
        async16(gp, &sm[2560 + w * 512 + rr * 2048]);
      }
    }
    __syncthreads();
    bfx8 af[2], bf[9];
#pragma unroll
    for (int mf = 0; mf < 2; ++mf)
      af[mf] = *(const bfx8*)&sm[(wm * 32 + mf * 16 + l15) * 40 + quad * 8];
#pragma unroll
    for (int nf = 0; nf < 9; ++nf)
      bf[nf] = *(const bfx8*)&sm[2560 + (wn * 144 + nf * 16 + l15) * 32 + quad * 8];
#pragma unroll
    for (int mf = 0; mf < 2; ++mf)
#pragma unroll
      for (int nf = 0; nf < 9; ++nf)
        acc[mf][nf] = __builtin_amdgcn_mfma_f32_16x16x32_bf16(af[mf], bf[nf], acc[mf][nf], 0, 0, 0);
    __syncthreads();
  }
#pragma unroll
  for (int mf = 0; mf < 2; ++mf)
#pragma unroll
    for (int nf = 0; nf < 9; ++nf)
#pragma unroll
      for (int r = 0; r < 4; ++r) {
        const size_t row = (size_t)m0 + wm * 32 + mf * 16 + quad * 4 + r;
        Q[row * K2PAD + wn * 144 + nf * 16 + l15] = f2bf(acc[mf][nf][r]);
      }
}

// ---------------------------------------------------------------- attention
// block = one batch row; wave = one head; lanes cover d=lane (+64+lane for lane<4)
__global__ __launch_bounds__(256) void attn_k(
    const unsigned short* __restrict__ Q, const unsigned short* __restrict__ KV,
    const int* __restrict__ masks, unsigned short* __restrict__ Attn, int b0) {
  __shared__ unsigned short kvb[20 * 552];  // row stride 552 bf16 (1104 B, 16B-aligned)
  __shared__ unsigned short qb[272];
  __shared__ int mb[20];
  const int t = threadIdx.x;
  const int bl = blockIdx.x;
  const int b = b0 + bl;
#pragma unroll
  for (int p = 0; p < 6; ++p) {
    int idx = p * 256 + t;
    int n = idx / 68;
    int off = idx % 68;
    if (n < 20) {
      usx8 v = *(const usx8*)((const char*)KV + ((size_t)bl * 20 + n) * 1088 + (size_t)off * 16);
      *(usx8*)((char*)kvb + n * 1104 + off * 16) = v;
    }
  }
  if (t < 34) {
    usx8 v = *(const usx8*)((const char*)Q + (size_t)b * 576 + t * 16);
    *(usx8*)((char*)qb + t * 16) = v;
  }
  if (t < 20) mb[t] = masks[b * 20 + t];
  if (t < 16) Attn[(size_t)b * K2PAD + 272 + t] = 0;  // zero K-pad for resid GEMM
  __syncthreads();
  const int h = t >> 6, l = t & 63;
  const bool hi = (l < 4);
  const float q1 = bf2f(qb[h * 68 + l]);
  const float q2 = hi ? bf2f(qb[h * 68 + 64 + l]) : 0.f;
  float s[20];
#pragma unroll
  for (int n = 0; n < 20; ++n) {
    float p = q1 * bf2f(kvb[n * 552 + h * 68 + l]);
    if (hi) p += q2 * bf2f(kvb[n * 552 + h * 68 + 64 + l]);
#pragma unroll
    for (int o = 32; o > 0; o >>= 1) p += __shfl_xor(p, o);
    s[n] = p;
  }
  const float scale = 0.12126781251816648f;  // 68^-0.5
  float mx = -1e30f;
#pragma unroll
  for (int n = 0; n < 20; ++n) {
    s[n] = mb[n] ? s[n] * scale : -1e10f;
    mx = fmaxf(mx, s[n]);
  }
  float sum = 0.f;
#pragma unroll
  for (int n = 0; n < 20; ++n) { s[n] = __expf(s[n] - mx); sum += s[n]; }
  const float inv = 1.f / sum;
  float o1 = 0.f, o2 = 0.f;
#pragma unroll
  for (int n = 0; n < 20; ++n) {
    const float pn = s[n] * inv;
    o1 += pn * bf2f(kvb[n * 552 + 272 + h * 68 + l]);
    if (hi) o2 += pn * bf2f(kvb[n * 552 + 272 + h * 68 + 64 + l]);
  }
  Attn[(size_t)b * K2PAD + h * 68 + l] = f2bf(o1);
  if (hi) Attn[(size_t)b * K2PAD + h * 68 + 64 + l] = f2bf(o2);
}

// ---------------------------------------------------------------- residual FC + LayerNorm
__global__ __launch_bounds__(256) void resid_ln(
    const unsigned short* __restrict__ Attn, const unsigned short* __restrict__ Br,
    const float* __restrict__ nodeF, const float* __restrict__ timeF,
    const float* __restrict__ brv, const float* __restrict__ gammav,
    const float* __restrict__ betav, float* __restrict__ Out) {
  __shared__ unsigned short sm[11264];  // A[64][32] @0 | B[288][32] @2048
  __shared__ float rsum[128], rsq[128];
  const int t = threadIdx.x;
  const int w = t >> 6, l = t & 63, l15 = l & 15, quad = l >> 4;
  const int wm = w >> 1, wn = w & 1;
  const int m0 = blockIdx.x * 64;
  f32x4 acc[2][9];
#pragma unroll
  for (int i = 0; i < 2; ++i)
#pragma unroll
    for (int j = 0; j < 9; ++j) acc[i][j] = (f32x4){0.f, 0.f, 0.f, 0.f};

  for (int k0 = 0; k0 < K2PAD; k0 += 32) {
    {  // A stage: 64 rows x 64 B, bf16 direct-to-LDS
      const int lin = t * 16;
      const int ar = lin >> 6;
      const int kb = lin & 63;
      async16((const char*)Attn + ((size_t)(m0 + ar) * K2PAD + k0) * 2 + kb, &sm[w * 512]);
    }
#pragma unroll
    for (int rr = 0; rr < 5; ++rr) {
      const int i16 = rr * 256 + t;
      if (i16 < 1152) {
        const int col = i16 >> 2;
        const int kb  = (i16 & 3) * 16;
        const char* gp = (const char*)Br + ((size_t)col * K2PAD + k0) * 2 + kb;
        async16(gp, &sm[2048 + w * 512 + rr * 2048]);
      }
    }
    __syncthreads();
    bfx8 af[2], bf[9];
#pragma unroll
    for (int mf = 0; mf < 2; ++mf)
      af[mf] = *(const bfx8*)&sm[(wm * 32 + mf * 16 + l15) * 32 + quad * 8];
#pragma unroll
    for (int nf = 0; nf < 9; ++nf)
      bf[nf] = *(const bfx8*)&sm[2048 + (wn * 144 + nf * 16 + l15) * 32 + quad * 8];
#pragma unroll
    for (int mf = 0; mf < 2; ++mf)
#pragma unroll
      for (int nf = 0; nf < 9; ++nf)
        acc[mf][nf] = __builtin_amdgcn_mfma_f32_16x16x32_bf16(af[mf], bf[nf], acc[mf][nf], 0, 0, 0);
    __syncthreads();
  }
  // epilogue: x = gemm + br + residual ; LN over 272 cols per row
  float sums[2][4], sqs[2][4];
#pragma unroll
  for (int mf = 0; mf < 2; ++mf)
#pragma unroll
    for (int r = 0; r < 4; ++r) { sums[mf][r] = 0.f; sqs[mf][r] = 0.f; }
#pragma unroll
  for (int mf = 0; mf < 2; ++mf)
#pragma unroll
    for (int nf = 0; nf < 9; ++nf) {
      const int col = wn * 144 + nf * 16 + l15;
      if (col < OUT_D) {
        const float bias = brv[col];
#pragma unroll
        for (int r = 0; r < 4; ++r) {
          const long row = m0 + wm * 32 + mf * 16 + quad * 4 + r;
          const float res = (col < NODE_D) ? nodeF[row * NODE_D + col]
                                           : timeF[row * TIME_D + (col - NODE_D)];
          const float x = acc[mf][nf][r] + bias + res;
          acc[mf][nf][r] = x;
          sums[mf][r] += x;
          sqs[mf][r]  += x * x;
        }
      }
    }
#pragma unroll
  for (int mf = 0; mf < 2; ++mf)
#pragma unroll
    for (int r = 0; r < 4; ++r) {
      float s = sums[mf][r], qq = sqs[mf][r];
#pragma unroll
      for (int o = 1; o < 16; o <<= 1) { s += __shfl_xor(s, o); qq += __shfl_xor(qq, o); }
      if (l15 == 0) {
        const int rl = wm * 32 + mf * 16 + quad * 4 + r;
        rsum[rl * 2 + wn] = s;
        rsq[rl * 2 + wn]  = qq;
      }
    }
  __syncthreads();
  float mean_[2][4], rstd_[2][4];
#pragma unroll
  for (int mf = 0; mf < 2; ++mf)
#pragma unroll
    for (int r = 0; r < 4; ++r) {
      const int rl = wm * 32 + mf * 16 + quad * 4 + r;
      const float mean = (rsum[rl * 2] + rsum[rl * 2 + 1]) * (1.f / OUT_D);
      const float var  = (rsq[rl * 2] + rsq[rl * 2 + 1]) * (1.f / OUT_D) - mean * mean;
      mean_[mf][r] = mean;
      rstd_[mf][r] = rsqrtf(var + 1e-5f);
    }
#pragma unroll
  for (int mf = 0; mf < 2; ++mf)
#pragma unroll
    for (int nf = 0; nf < 9; ++nf) {
      const int col = wn * 144 + nf * 16 + l15;
      if (col < OUT_D) {
        const float g_ = gammav[col], b_ = betav[col];
#pragma unroll
        for (int r = 0; r < 4; ++r) {
          const long row = m0 + wm * 32 + mf * 16 + quad * 4 + r;
          Out[row * OUT_D + col] = (acc[mf][nf][r] - mean_[mf][r]) * rstd_[mf][r] * g_ + b_;
        }
      }
    }
}

// ---------------------------------------------------------------- launch
extern "C" void kernel_launch(void* const* d_in, const int* in_sizes, int n_in,
                              void* d_out, int out_size, void* d_ws, size_t ws_size,
                              hipStream_t stream) {
  const float* nodeF = (const float*)d_in[0];
  const float* ntime = (const float*)d_in[1];
  const float* nbrF  = (const float*)d_in[2];
  const float* nbrT  = (const float*)d_in[3];
  const float* nbrE  = (const float*)d_in[4];
  const int*   mask  = (const int*)d_in[5];
  const float* Wq = (const float*)d_in[6];
  const float* Wk = (const float*)d_in[7];
  const float* Wv = (const float*)d_in[8];
  const float* Wr = (const float*)d_in[9];
  const float* brv = (const float*)d_in[10];
  const float* gv  = (const float*)d_in[11];
  const float* bv  = (const float*)d_in[12];
  float* out = (float*)d_out;

  char* p = (char*)d_ws;
  auto take = [&](size_t bytes) {
    char* q = p; p += (bytes + 255) & ~(size_t)255; return q;
  };
  unsigned short* Bkv = (unsigned short*)take((size_t)NPAD * KPAD * 2);
  unsigned short* Bq  = (unsigned short*)take((size_t)K2PAD * K2PAD * 2);
  unsigned short* Brm = (unsigned short*)take((size_t)K2PAD * K2PAD * 2);
  unsigned short* Qm  = (unsigned short*)take((size_t)B_TOT * K2PAD * 2);
  unsigned short* At  = (unsigned short*)take((size_t)B_TOT * K2PAD * 2);
  unsigned short* KV  = (unsigned short*)take((size_t)CROWS * 2 * OUT_D * 2);

  pack_w<<<dim3(1120), dim3(256), 0, stream>>>(Wk, Wv, Wq, Wr, Bkv, Bq, Brm);
  q_gemm<<<dim3(B_TOT / 64), dim3(256), 0, stream>>>(nodeF, ntime, Bq, Qm);
  for (int c = 0; c < CHUNKS; ++c) {
    kv_gemm<<<dim3(NPAD / 128, CROWS / 128), dim3(256), 0, stream>>>(
        nbrF, nbrE, nbrT, Bkv, KV, c * CROWS);
    attn_k<<<dim3(CB), dim3(256), 0, stream>>>(Qm, KV, mask, At, c * CB);
  }
  resid_ln<<<dim3(B_TOT / 64), dim3(256), 0, stream>>>(
      At, Brm, nodeF, ntime, brv, gv, bv, out);
}

// Round 2
// 1189.577 us; speedup vs baseline: 1.1918x; 1.1918x over previous
//
#include <hip/hip_runtime.h>
#include <stdint.h>

#define B_TOT   16384
#define NNBR    20
#define NODE_D  172
#define TIME_D  100
#define KEY_D   444
#define OUT_D   272
#define KPAD    448
#define CHUNKS  4
#define CB      (B_TOT/CHUNKS)   // 4096 batch rows per chunk
#define CROWS   (CB*NNBR)        // 81920 kv rows per chunk
#define K2PAD   288
#define SA_KV   456              // A panel LDS stride (elems), kv_gemm
#define SA_Q    296              // A panel LDS stride (elems), q/resid

typedef __attribute__((ext_vector_type(4))) float          f32x4;
typedef __attribute__((ext_vector_type(8))) short          bfx8;
typedef __attribute__((ext_vector_type(8))) unsigned short usx8;

__device__ __forceinline__ unsigned short f2bf(float f) {
  union { float f; unsigned u; } v; v.f = f;
  return (unsigned short)((v.u + 0x7FFFu + ((v.u >> 16) & 1u)) >> 16);  // RTNE
}
__device__ __forceinline__ float bf2f(unsigned short h) {
  union { unsigned u; float f; } v; v.u = ((unsigned)h) << 16; return v.f;
}
__device__ __forceinline__ usx8 pack8(f32x4 a, f32x4 b) {
  usx8 h;
  h[0] = f2bf(a[0]); h[1] = f2bf(a[1]); h[2] = f2bf(a[2]); h[3] = f2bf(a[3]);
  h[4] = f2bf(b[0]); h[5] = f2bf(b[1]); h[6] = f2bf(b[2]); h[7] = f2bf(b[3]);
  return h;
}

// ---------------------------------------------------------------- pack weights
__global__ __launch_bounds__(256) void pack_w(
    const float* __restrict__ Wk, const float* __restrict__ Wv,
    const float* __restrict__ Wq, const float* __restrict__ Wr,
    unsigned short* __restrict__ Bkv, unsigned short* __restrict__ Bq,
    unsigned short* __restrict__ Br) {
  int idx = blockIdx.x * 256 + threadIdx.x;
  if (idx < 544 * KPAD) {
    int j = idx / KPAD, k = idx % KPAD;
    float v = 0.f;
    if (k < KEY_D) {
      if (j < OUT_D) v = Wk[j * KEY_D + k];
      else           v = Wv[(j - OUT_D) * KEY_D + k];
    }
    Bkv[idx] = f2bf(v);
  }
  if (idx < K2PAD * K2PAD) {
    int j = idx / K2PAD, k = idx % K2PAD;
    bool in = (j < OUT_D) && (k < OUT_D);
    Bq[idx] = f2bf(in ? Wq[j * OUT_D + k] : 0.f);
    Br[idx] = f2bf(in ? Wr[j * OUT_D + k] : 0.f);
  }
}

// ---------------------------------------------------------------- K/V GEMM
// Block: 64 kv-rows x 544 cols. A panel staged to LDS once; barrier-free k-loop:
// B frags global->reg (L2-hot Bkv), A frags LDS, 1-iter prefetch. Wave w owns a
// 32-col slice (no cross-wave B duplication).
__device__ __forceinline__ f32x4 ld_kv(const float* pn, const float* pe,
                                       const float* pt, int k) {
  if (k < NODE_D)     return *(const f32x4*)(pn + k);
  if (k < 2*NODE_D)   return *(const f32x4*)(pe + (k - NODE_D));
  if (k < KEY_D)      return *(const f32x4*)(pt + (k - 2*NODE_D));
  return (f32x4){0.f, 0.f, 0.f, 0.f};
}

__global__ __launch_bounds__(256) void kv_gemm(
    const float* __restrict__ nbrF, const float* __restrict__ edgeF,
    const float* __restrict__ timeF, const unsigned short* __restrict__ Bkv,
    unsigned short* __restrict__ KV, int row0) {
  __shared__ unsigned short sA[64 * SA_KV];      // 58368 B
  __shared__ unsigned short scr[4 * 64 * 40];    // 20480 B, per-wave epilogue bounce
  const int t = threadIdx.x;
  const int w = t >> 6, l = t & 63, l15 = l & 15, quad = l >> 4;
  const int m0 = blockIdx.x * 64;
  // ---- stage A panel (once)
  {
    const int r = t >> 2, qt = t & 3;
    const long grow = (long)row0 + m0 + r;
    const float* pn = nbrF + grow * NODE_D;
    const float* pe = edgeF + grow * NODE_D;
    const float* pt = timeF + grow * TIME_D;
#pragma unroll
    for (int i = 0; i < 14; ++i) {
      const int k = (qt + 4 * i) * 8;
      f32x4 v0 = ld_kv(pn, pe, pt, k);
      f32x4 v1 = ld_kv(pn, pe, pt, k + 4);
      *(usx8*)&sA[r * SA_KV + k] = pack8(v0, v1);
    }
  }
  __syncthreads();

  const unsigned short* ap = sA + l15 * SA_KV + quad * 8;
  for (int nt = 0; nt < 5; ++nt) {
    if (nt == 4 && w > 0) continue;     // cols >= 544 are pad; wave-uniform skip
    const int c0 = nt * 128 + w * 32;
    const unsigned short* bp = Bkv + (size_t)(c0 + l15) * KPAD + quad * 8;
    f32x4 acc[4][2];
#pragma unroll
    for (int mf = 0; mf < 4; ++mf) { acc[mf][0] = (f32x4){0,0,0,0}; acc[mf][1] = (f32x4){0,0,0,0}; }
    bfx8 bc[2], ac[4];
    bc[0] = *(const bfx8*)bp;
    bc[1] = *(const bfx8*)(bp + 16 * KPAD);
#pragma unroll
    for (int mf = 0; mf < 4; ++mf) ac[mf] = *(const bfx8*)(ap + mf * 16 * SA_KV);
#pragma unroll
    for (int k0 = 0; k0 < KPAD; k0 += 32) {
      const int kn = (k0 + 32 < KPAD) ? k0 + 32 : 0;
      bfx8 bn[2], an[4];
      bn[0] = *(const bfx8*)(bp + kn);
      bn[1] = *(const bfx8*)(bp + 16 * KPAD + kn);
#pragma unroll
      for (int mf = 0; mf < 4; ++mf) an[mf] = *(const bfx8*)(ap + mf * 16 * SA_KV + kn);
#pragma unroll
      for (int mf = 0; mf < 4; ++mf) {
        acc[mf][0] = __builtin_amdgcn_mfma_f32_16x16x32_bf16(ac[mf], bc[0], acc[mf][0], 0, 0, 0);
        acc[mf][1] = __builtin_amdgcn_mfma_f32_16x16x32_bf16(ac[mf], bc[1], acc[mf][1], 0, 0, 0);
      }
#pragma unroll
      for (int mf = 0; mf < 4; ++mf) ac[mf] = an[mf];
      bc[0] = bn[0]; bc[1] = bn[1];
    }
    // ---- epilogue: wave-private LDS bounce -> 16B-granule global stores
    unsigned short* sw = scr + w * 2560;
#pragma unroll
    for (int mf = 0; mf < 4; ++mf)
#pragma unroll
      for (int nf = 0; nf < 2; ++nf)
#pragma unroll
        for (int r = 0; r < 4; ++r)
          sw[(mf * 16 + quad * 4 + r) * 40 + nf * 16 + l15] = f2bf(acc[mf][nf][r]);
#pragma unroll
    for (int j = 0; j < 4; ++j) {
      const int idx = j * 64 + l;
      const int row = idx >> 2, o = idx & 3;
      usx8 v = *(const usx8*)(sw + row * 40 + o * 8);
      *(usx8*)((char*)KV + (size_t)(m0 + row) * 1088 + (size_t)(c0 + o * 8) * 2) = v;
    }
  }
}

// ---------------------------------------------------------------- Q GEMM
// Block 64 rows; wave = 16 rows x all 272 cols (17 frags). Barrier-free k-loop,
// B from global (L2-hot).
__global__ __launch_bounds__(256) void q_gemm(
    const float* __restrict__ nodeF, const float* __restrict__ timeF,
    const unsigned short* __restrict__ Bq, unsigned short* __restrict__ Q) {
  __shared__ unsigned short sA[64 * SA_Q];  // 37888 B
  const int t = threadIdx.x;
  const int w = t >> 6, l = t & 63, l15 = l & 15, quad = l >> 4;
  const int m0 = blockIdx.x * 64;
  {
    const int r = t >> 2, qt = t & 3;
    const float* pn = nodeF + (size_t)(m0 + r) * NODE_D;
    const float* pt = timeF + (size_t)(m0 + r) * TIME_D;
#pragma unroll
    for (int i = 0; i < 9; ++i) {
      const int k = (qt + 4 * i) * 8;
      f32x4 v0, v1;
      v0 = (k < NODE_D) ? *(const f32x4*)(pn + k)
         : (k < OUT_D)  ? *(const f32x4*)(pt + (k - NODE_D)) : (f32x4){0,0,0,0};
      int k4 = k + 4;
      v1 = (k4 < NODE_D) ? *(const f32x4*)(pn + k4)
         : (k4 < OUT_D)  ? *(const f32x4*)(pt + (k4 - NODE_D)) : (f32x4){0,0,0,0};
      *(usx8*)&sA[r * SA_Q + k] = pack8(v0, v1);
    }
  }
  __syncthreads();
  const unsigned short* ap = sA + (w * 16 + l15) * SA_Q + quad * 8;
  const unsigned short* bp = Bq + (size_t)l15 * K2PAD + quad * 8;
  f32x4 acc[17];
#pragma unroll
  for (int nf = 0; nf < 17; ++nf) acc[nf] = (f32x4){0,0,0,0};
#pragma unroll
  for (int k0 = 0; k0 < K2PAD; k0 += 32) {
    bfx8 a = *(const bfx8*)(ap + k0);
#pragma unroll
    for (int nf = 0; nf < 17; ++nf) {
      bfx8 b = *(const bfx8*)(bp + nf * 16 * K2PAD + k0);
      acc[nf] = __builtin_amdgcn_mfma_f32_16x16x32_bf16(a, b, acc[nf], 0, 0, 0);
    }
  }
#pragma unroll
  for (int nf = 0; nf < 17; ++nf)
#pragma unroll
    for (int r = 0; r < 4; ++r) {
      const size_t row = m0 + w * 16 + quad * 4 + r;
      Q[row * K2PAD + nf * 16 + l15] = f2bf(acc[nf][r]);
    }
}

// ---------------------------------------------------------------- attention
// Block = 1 batch row, wave = head. No LDS, no barriers; KV reads L3-hot and
// 128B-coalesced per (n,h).
__global__ __launch_bounds__(256) void attn_k(
    const unsigned short* __restrict__ Q, const unsigned short* __restrict__ KV,
    const int* __restrict__ masks, unsigned short* __restrict__ At, int b0) {
  const int bl = blockIdx.x;
  const int b = b0 + bl;
  const int h = threadIdx.x >> 6, l = threadIdx.x & 63;
  const bool hi = (l < 4);
  const unsigned short* kvb = KV + (size_t)bl * 20 * 544 + h * 68;
  const unsigned short* qp  = Q + (size_t)b * K2PAD + h * 68;
  const float q1 = bf2f(qp[l]);
  const float q2 = hi ? bf2f(qp[64 + l]) : 0.f;
  int mk[20];
#pragma unroll
  for (int n = 0; n < 20; ++n) mk[n] = masks[b * 20 + n];
  float s[20];
#pragma unroll
  for (int n = 0; n < 20; ++n) {
    const unsigned short* kn = kvb + n * 544;
    float p = q1 * bf2f(kn[l]);
    if (hi) p += q2 * bf2f(kn[64 + l]);
#pragma unroll
    for (int o = 32; o > 0; o >>= 1) p += __shfl_xor(p, o);
    s[n] = p;
  }
  const float scale = 0.12126781251816648f;  // 68^-0.5
  float mx = -1e30f;
#pragma unroll
  for (int n = 0; n < 20; ++n) {
    s[n] = mk[n] ? s[n] * scale : -1e10f;
    mx = fmaxf(mx, s[n]);
  }
  float sum = 0.f;
#pragma unroll
  for (int n = 0; n < 20; ++n) { s[n] = __expf(s[n] - mx); sum += s[n]; }
  const float inv = 1.f / sum;
  float o1 = 0.f, o2 = 0.f;
#pragma unroll
  for (int n = 0; n < 20; ++n) {
    const float pn = s[n] * inv;
    const unsigned short* vn = kvb + n * 544 + 272;
    o1 += pn * bf2f(vn[l]);
    if (hi) o2 += pn * bf2f(vn[64 + l]);
  }
  At[(size_t)b * K2PAD + h * 68 + l] = f2bf(o1);
  if (hi) At[(size_t)b * K2PAD + h * 68 + 64 + l] = f2bf(o2);
  if (threadIdx.x < 16) At[(size_t)b * K2PAD + 272 + threadIdx.x] = 0;
}

// ---------------------------------------------------------------- residual FC + LN
// Same barrier-free shape as q_gemm; LN is wave-local (all 272 cols of a row
// live in one 16-lane group).
__global__ __launch_bounds__(256) void resid_ln(
    const unsigned short* __restrict__ At, const unsigned short* __restrict__ Br,
    const float* __restrict__ nodeF, const float* __restrict__ timeF,
    const float* __restrict__ brv, const float* __restrict__ gammav,
    const float* __restrict__ betav, float* __restrict__ Out) {
  __shared__ unsigned short sA[64 * SA_Q];
  const int t = threadIdx.x;
  const int w = t >> 6, l = t & 63, l15 = l & 15, quad = l >> 4;
  const int m0 = blockIdx.x * 64;
#pragma unroll
  for (int i = 0; i < 9; ++i) {
    const int idx = i * 256 + t;
    const int row = idx / 36, g = idx % 36;
    usx8 v = *(const usx8*)(At + (size_t)(m0 + row) * K2PAD + g * 8);
    *(usx8*)&sA[row * SA_Q + g * 8] = v;
  }
  __syncthreads();
  const unsigned short* ap = sA + (w * 16 + l15) * SA_Q + quad * 8;
  const unsigned short* bp = Br + (size_t)l15 * K2PAD + quad * 8;
  f32x4 acc[17];
#pragma unroll
  for (int nf = 0; nf < 17; ++nf) acc[nf] = (f32x4){0,0,0,0};
#pragma unroll
  for (int k0 = 0; k0 < K2PAD; k0 += 32) {
    bfx8 a = *(const bfx8*)(ap + k0);
#pragma unroll
    for (int nf = 0; nf < 17; ++nf) {
      bfx8 b = *(const bfx8*)(bp + nf * 16 * K2PAD + k0);
      acc[nf] = __builtin_amdgcn_mfma_f32_16x16x32_bf16(a, b, acc[nf], 0, 0, 0);
    }
  }
  float sum[4] = {0.f, 0.f, 0.f, 0.f}, sq[4] = {0.f, 0.f, 0.f, 0.f};
#pragma unroll
  for (int nf = 0; nf < 17; ++nf) {
    const int col = nf * 16 + l15;
    const float bias = brv[col];
#pragma unroll
    for (int r = 0; r < 4; ++r) {
      const size_t row = m0 + w * 16 + quad * 4 + r;
      const float res = (col < NODE_D) ? nodeF[row * NODE_D + col]
                                       : timeF[row * TIME_D + (col - NODE_D)];
      const float x = acc[nf][r] + bias + res;
      acc[nf][r] = x;
      sum[r] += x; sq[r] += x * x;
    }
  }
#pragma unroll
  for (int r = 0; r < 4; ++r)
#pragma unroll
    for (int o = 1; o < 16; o <<= 1) {
      sum[r] += __shfl_xor(sum[r], o);
      sq[r]  += __shfl_xor(sq[r], o);
    }
  float mean[4], rstd[4];
#pragma unroll
  for (int r = 0; r < 4; ++r) {
    mean[r] = sum[r] * (1.f / OUT_D);
    const float var = sq[r] * (1.f / OUT_D) - mean[r] * mean[r];
    rstd[r] = rsqrtf(var + 1e-5f);
  }
#pragma unroll
  for (int nf = 0; nf < 17; ++nf) {
    const int col = nf * 16 + l15;
    const float g_ = gammav[col], b_ = betav[col];
#pragma unroll
    for (int r = 0; r < 4; ++r) {
      const size_t row = m0 + w * 16 + quad * 4 + r;
      Out[row * OUT_D + col] = (acc[nf][r] - mean[r]) * rstd[r] * g_ + b_;
    }
  }
}

// ---------------------------------------------------------------- launch
extern "C" void kernel_launch(void* const* d_in, const int* in_sizes, int n_in,
                              void* d_out, int out_size, void* d_ws, size_t ws_size,
                              hipStream_t stream) {
  const float* nodeF = (const float*)d_in[0];
  const float* ntime = (const float*)d_in[1];
  const float* nbrF  = (const float*)d_in[2];
  const float* nbrT  = (const float*)d_in[3];
  const float* nbrE  = (const float*)d_in[4];
  const int*   mask  = (const int*)d_in[5];
  const float* Wq = (const float*)d_in[6];
  const float* Wk = (const float*)d_in[7];
  const float* Wv = (const float*)d_in[8];
  const float* Wr = (const float*)d_in[9];
  const float* brv = (const float*)d_in[10];
  const float* gv  = (const float*)d_in[11];
  const float* bv  = (const float*)d_in[12];
  float* out = (float*)d_out;

  char* p = (char*)d_ws;
  auto take = [&](size_t bytes) {
    char* q = p; p += (bytes + 255) & ~(size_t)255; return q;
  };
  unsigned short* Bkv = (unsigned short*)take((size_t)640 * KPAD * 2);
  unsigned short* Bq  = (unsigned short*)take((size_t)K2PAD * K2PAD * 2);
  unsigned short* Brm = (unsigned short*)take((size_t)K2PAD * K2PAD * 2);
  unsigned short* Qm  = (unsigned short*)take((size_t)B_TOT * K2PAD * 2);
  unsigned short* At  = (unsigned short*)take((size_t)B_TOT * K2PAD * 2);
  unsigned short* KV  = (unsigned short*)take((size_t)CROWS * 2 * OUT_D * 2);

  pack_w<<<dim3(1120), dim3(256), 0, stream>>>(Wk, Wv, Wq, Wr, Bkv, Bq, Brm);
  q_gemm<<<dim3(B_TOT / 64), dim3(256), 0, stream>>>(nodeF, ntime, Bq, Qm);
  for (int c = 0; c < CHUNKS; ++c) {
    kv_gemm<<<dim3(CROWS / 64), dim3(256), 0, stream>>>(
        nbrF, nbrE, nbrT, Bkv, KV, c * CROWS);
    attn_k<<<dim3(CB), dim3(256), 0, stream>>>(Qm, KV, mask, At, c * CB);
  }
  resid_ln<<<dim3(B_TOT / 64), dim3(256), 0, stream>>>(
      At, Brm, nodeF, ntime, brv, gv, bv, out);
}